// Round 10
// baseline (585.257 us; speedup 1.0000x reference)
//
#include <hip/hip_runtime.h>
#include <hip/hip_cooperative_groups.h>
#include <math.h>

namespace cg = cooperative_groups;

#define DIMC 256
#define NH 8
#define NPIX 16384          // 128*128
#define BATCH 16
#define ATT_SCALE 0.17677669529663687f   // 1/sqrt(32)
#define LN_EPS 1e-5f
#define NBLK_S 4            // n-splits in s pass
#define NBL 512             // cooperative grid size (2 blocks/CU)

// ---------------------------------------------------------------------------
// Mega-kernel: P0 qk -> P1 attn -> P2 s-partials -> P3 scale -> P4 out,
// separated by grid.sync(). All hot-phase access patterns identical to the
// proven R9 kernels. Block-divergent phases guard on blockIdx only; all
// grid.sync() calls are unconditional.
// ---------------------------------------------------------------------------
__global__ __launch_bounds__(256) void k_mega(
    const float* __restrict__ fm,    const float* __restrict__ audio,
    const float* __restrict__ Wq,    const float* __restrict__ Wkv,
    const float* __restrict__ Wp,    const float* __restrict__ bp,
    const float* __restrict__ lng,   const float* __restrict__ lnb,
    float* __restrict__ out,         float* __restrict__ qkT,
    float* __restrict__ a,           float* __restrict__ s_part,
    float* __restrict__ scale)
{
    cg::grid_group grid = cg::this_grid();
    const int blk = blockIdx.x;
    const int t   = threadIdx.x;

    __shared__ float aud[DIMC];
    __shared__ float qL[DIMC];
    __shared__ float red[DIMC * NH];     // P2 reduction (8 KB)
    __shared__ float sL[NH][DIMC];       // P3
    __shared__ float xL[DIMC];           // P3
    __shared__ float red8[8];            // P3
    __shared__ float mu_s, var_s;        // P3

    // ======== P0: qkT[b][c][h], 512 blocks = 16 b x 32 cslabs(8 c) ========
    {
        const int b  = blk >> 5;
        const int c0 = (blk & 31) * 8;
        aud[t] = audio[b * DIMC + t];
        __syncthreads();
        {   // q[i], i = t (redundant per-b across 32 blocks; trivial)
            const float* wr = Wq + (size_t)t * DIMC;
            float acc = 0.f;
            for (int c = 0; c < DIMC; c += 4) {
                float4 w = *(const float4*)(wr + c);
                acc = fmaf(w.x, aud[c],     acc);
                acc = fmaf(w.y, aud[c + 1], acc);
                acc = fmaf(w.z, aud[c + 2], acc);
                acc = fmaf(w.w, aud[c + 3], acc);
            }
            qL[t] = acc;
        }
        __syncthreads();
        if (t < 64) {
            const int c = c0 + (t & 7);
            const int h = t >> 3;
            float acc = 0.f;
#pragma unroll
            for (int d = 0; d < 32; ++d)
                acc = fmaf(qL[h * 32 + d], Wkv[(size_t)(h * 32 + d) * DIMC + c], acc);
            qkT[((size_t)b * DIMC + c) * NH + h] = ATT_SCALE * acc;
        }
    }
    grid.sync();

    // ======== P1: attn (R9 k_attn verbatim; 512 blocks) ========
    {
        const int b    = blk >> 5;
        const int nblk = blk & 31;
        const int n0   = nblk * 512 + t * 2;
        const float* fmb = fm + (size_t)b * DIMC * NPIX + n0;
        const float* qb  = qkT + (size_t)b * DIMC * NH;

        float a0[NH], a1[NH];
#pragma unroll
        for (int h = 0; h < NH; ++h) { a0[h] = 0.f; a1[h] = 0.f; }

#pragma unroll 8
        for (int c = 0; c < DIMC; ++c) {
            float2 v  = *(const float2*)(fmb + (size_t)c * NPIX);
            float4 q0 = *(const float4*)(qb + c * NH);     // uniform -> s_load
            float4 q1 = *(const float4*)(qb + c * NH + 4);
            a0[0] = fmaf(v.x, q0.x, a0[0]); a1[0] = fmaf(v.y, q0.x, a1[0]);
            a0[1] = fmaf(v.x, q0.y, a0[1]); a1[1] = fmaf(v.y, q0.y, a1[1]);
            a0[2] = fmaf(v.x, q0.z, a0[2]); a1[2] = fmaf(v.y, q0.z, a1[2]);
            a0[3] = fmaf(v.x, q0.w, a0[3]); a1[3] = fmaf(v.y, q0.w, a1[3]);
            a0[4] = fmaf(v.x, q1.x, a0[4]); a1[4] = fmaf(v.y, q1.x, a1[4]);
            a0[5] = fmaf(v.x, q1.y, a0[5]); a1[5] = fmaf(v.y, q1.y, a1[5]);
            a0[6] = fmaf(v.x, q1.z, a0[6]); a1[6] = fmaf(v.y, q1.z, a1[6]);
            a0[7] = fmaf(v.x, q1.w, a0[7]); a1[7] = fmaf(v.y, q1.w, a1[7]);
        }

#pragma unroll
        for (int h = 0; h < NH; ++h) {
            float2 o;
            o.x = rintf(fminf(fmaxf(a0[h], 0.f), 4.f)) * 0.25f;
            o.y = rintf(fminf(fmaxf(a1[h], 0.f), 4.f)) * 0.25f;
            *(float2*)(a + ((size_t)b * NH + h) * NPIX + n0) = o;
        }
    }
    grid.sync();

    // ======== P2: s partials (R9 k_s, 1024 units, 2 per block) ========
    for (int u = 0; u < 2; ++u) {
        const int d    = blk * 2 + u;
        const int vb   = (d & 7) * 128 + (d >> 3);   // XCD-bijective swizzle
        const int b    = vb >> 6;
        const int nblk = (vb >> 4) & 3;
        const int cblk = vb & 15;
        const int c_l  = t >> 4;
        const int nq   = t & 15;
        const int c    = cblk * 16 + c_l;

        const float* fr = fm + ((size_t)b * DIMC + c) * NPIX + nblk * 4096 + nq * 4;
        const float* ab = a + (size_t)b * NH * NPIX + nblk * 4096 + nq * 4;

        float acc[NH];
#pragma unroll
        for (int h = 0; h < NH; ++h) acc[h] = 0.f;

#pragma unroll 2
        for (int j = 0; j < 64; ++j) {
            float4 v = *(const float4*)(fr + j * 64);
#pragma unroll
            for (int h = 0; h < NH; ++h) {
                float4 av = *(const float4*)(ab + (size_t)h * NPIX + j * 64);
                acc[h] += fmaf(v.x, av.x, fmaf(v.y, av.y, fmaf(v.z, av.z, v.w * av.w)));
            }
        }

#pragma unroll
        for (int h = 0; h < NH; ++h) red[t * NH + h] = acc[h];
        __syncthreads();

        if (t < 128) {
            int cl = t >> 3, h = t & 7;
            float sum = 0.f;
#pragma unroll
            for (int q = 0; q < 16; ++q)
                sum += red[(cl * 16 + q) * NH + h];
            s_part[(((size_t)b * NBLK_S + nblk) * NH + h) * DIMC + cblk * 16 + cl] = sum;
        }
        __syncthreads();   // red reused by next unit
    }
    grid.sync();

    // ======== P3: scale (R9 k_scale; blocks 0..15 active) ========
    if (blk < BATCH) {
        const int b = blk;
        for (int h = 0; h < NH; ++h) {
            float acc = 0.f;
            for (int sl = 0; sl < NBLK_S; ++sl)
                acc += s_part[(((size_t)b * NBLK_S + sl) * NH + h) * DIMC + t];
            sL[h][t] = acc;
        }
        __syncthreads();

        {
            const float* wr = Wkv + (size_t)(DIMC + t) * DIMC;
            const float* sr = sL[t >> 5];
            float acc = 0.f;
            for (int cc = 0; cc < DIMC; cc += 4) {
                float4 w = *(const float4*)(wr + cc);
                acc = fmaf(w.x, sr[cc],     acc);
                acc = fmaf(w.y, sr[cc + 1], acc);
                acc = fmaf(w.z, sr[cc + 2], acc);
                acc = fmaf(w.w, sr[cc + 3], acc);
            }
            xL[t] = acc;
        }
        __syncthreads();

        float p;
        {
            const float* wr = Wp + (size_t)t * DIMC;
            float acc = 0.f;
            for (int i = 0; i < DIMC; i += 4) {
                float4 w = *(const float4*)(wr + i);
                acc = fmaf(w.x, xL[i],     acc);
                acc = fmaf(w.y, xL[i + 1], acc);
                acc = fmaf(w.z, xL[i + 2], acc);
                acc = fmaf(w.w, xL[i + 3], acc);
            }
            p = acc + bp[t];
        }

        int lane = t & 63, wid = t >> 6;
        float r = p;
#pragma unroll
        for (int off = 32; off > 0; off >>= 1) r += __shfl_down(r, off);
        if (lane == 0) red8[wid] = r;
        __syncthreads();
        if (t == 0) mu_s = (red8[0] + red8[1] + red8[2] + red8[3]) * (1.f / 256.f);
        __syncthreads();
        float mu = mu_s;
        float dd = p - mu;
        float r2 = dd * dd;
#pragma unroll
        for (int off = 32; off > 0; off >>= 1) r2 += __shfl_down(r2, off);
        if (lane == 0) red8[4 + wid] = r2;
        __syncthreads();
        if (t == 0) var_s = (red8[4] + red8[5] + red8[6] + red8[7]) * (1.f / 256.f);
        __syncthreads();

        float ln = dd * (1.0f / sqrtf(var_s + LN_EPS)) * lng[t] + lnb[t];
        scale[b * DIMC + t] = rintf(fminf(fmaxf(ln, 0.f), 4.f)) * 0.25f;
    }
    grid.sync();

    // ======== P4: out = fm * scale (grid-stride float4) ========
    {
        const size_t total4 = (size_t)BATCH * DIMC * NPIX / 4;   // 16,777,216
        const size_t stride = (size_t)NBL * 256;
        for (size_t i = (size_t)blk * 256 + t; i < total4; i += stride) {
            float4 v = *(const float4*)(fm + i * 4);
            float sval = scale[i >> 12];
            float4 o;
            o.x = v.x * sval; o.y = v.y * sval; o.z = v.z * sval; o.w = v.w * sval;
            *(float4*)(out + i * 4) = o;
        }
    }
}

// ---------------------------------------------------------------------------
extern "C" void kernel_launch(void* const* d_in, const int* in_sizes, int n_in,
                              void* d_out, int out_size, void* d_ws, size_t ws_size,
                              hipStream_t stream) {
    (void)in_sizes; (void)n_in; (void)out_size; (void)ws_size;
    const float* fm    = (const float*)d_in[0];
    const float* audio = (const float*)d_in[1];
    const float* Wq    = (const float*)d_in[2];
    const float* Wkv   = (const float*)d_in[3];
    const float* Wp    = (const float*)d_in[4];
    const float* bp    = (const float*)d_in[5];
    const float* lng   = (const float*)d_in[6];
    const float* lnb   = (const float*)d_in[7];
    float* out = (float*)d_out;

    char* ws = (char*)d_ws;
    float* qkT    = (float*)(ws);                                     // 128 KB
    float* a      = (float*)(ws + (size_t)131072);                    // 8 MB
    float* s_part = (float*)(ws + (size_t)131072 + 8388608);          // 512 KB
    float* scale  = (float*)(ws + (size_t)131072 + 8388608 + 524288); // 16 KB

    void* args[] = {
        (void*)&fm, (void*)&audio, (void*)&Wq, (void*)&Wkv,
        (void*)&Wp, (void*)&bp, (void*)&lng, (void*)&lnb,
        (void*)&out, (void*)&qkT, (void*)&a, (void*)&s_part, (void*)&scale
    };
    hipLaunchCooperativeKernel((const void*)k_mega, dim3(NBL), dim3(256),
                               args, 0, stream);
}

// Round 11
// 334.149 us; speedup vs baseline: 1.7515x; 1.7515x over previous
//
#include <hip/hip_runtime.h>
#include <math.h>

#define DIMC 256
#define NH 8
#define NPIX 16384          // 128*128
#define BATCH 16
#define ATT_SCALE 0.17677669529663687f   // 1/sqrt(32)
#define LN_EPS 1e-5f
#define NSLAB 32            // n-slabs in k_s (512 n each)

// ---------------------------------------------------------------------------
// K0: qkT[b][c][h] = SCALE * sum_d q[b][h*32+d] * Wkv[h*32+d][c]
// 512 blocks = 16 b x 32 c-slabs (8 c each). (Mega-P0 pattern, R10-verified.)
// ---------------------------------------------------------------------------
__global__ __launch_bounds__(256) void k_qk(const float* __restrict__ audio,
                                            const float* __restrict__ Wq,
                                            const float* __restrict__ Wkv,
                                            float* __restrict__ qkT) {
    const int blk = blockIdx.x;
    const int b   = blk >> 5;
    const int c0  = (blk & 31) * 8;
    const int t   = threadIdx.x;
    __shared__ float aud[DIMC];
    __shared__ float qL[DIMC];
    aud[t] = audio[b * DIMC + t];
    __syncthreads();
    {
        const float* wr = Wq + (size_t)t * DIMC;
        float acc = 0.f;
        for (int c = 0; c < DIMC; c += 4) {
            float4 w = *(const float4*)(wr + c);
            acc = fmaf(w.x, aud[c],     acc);
            acc = fmaf(w.y, aud[c + 1], acc);
            acc = fmaf(w.z, aud[c + 2], acc);
            acc = fmaf(w.w, aud[c + 3], acc);
        }
        qL[t] = acc;
    }
    __syncthreads();
    if (t < 64) {
        const int c = c0 + (t & 7);
        const int h = t >> 3;
        float acc = 0.f;
#pragma unroll
        for (int d = 0; d < 32; ++d)
            acc = fmaf(qL[h * 32 + d], Wkv[(size_t)(h * 32 + d) * DIMC + c], acc);
        qkT[((size_t)b * DIMC + c) * NH + h] = ATT_SCALE * acc;
    }
}

// ---------------------------------------------------------------------------
// K1: attn pass (R9 verbatim). 512 blocks x 256 thr, float2, unroll 8.
// ---------------------------------------------------------------------------
__global__ __launch_bounds__(256) void k_attn(const float* __restrict__ fm,
                                              const float* __restrict__ qkT,
                                              float* __restrict__ a) {
    int blk  = blockIdx.x;          // 512 = b*32 + nblk
    int b    = blk >> 5;
    int nblk = blk & 31;
    int t    = threadIdx.x;

    const int n0 = nblk * 512 + t * 2;
    const float* fmb = fm + (size_t)b * DIMC * NPIX + n0;
    const float* qb  = qkT + (size_t)b * DIMC * NH;

    float a0[NH], a1[NH];
#pragma unroll
    for (int h = 0; h < NH; ++h) { a0[h] = 0.f; a1[h] = 0.f; }

#pragma unroll 8
    for (int c = 0; c < DIMC; ++c) {
        float2 v  = *(const float2*)(fmb + (size_t)c * NPIX);
        float4 q0 = *(const float4*)(qb + c * NH);       // uniform -> s_load
        float4 q1 = *(const float4*)(qb + c * NH + 4);
        a0[0] = fmaf(v.x, q0.x, a0[0]); a1[0] = fmaf(v.y, q0.x, a1[0]);
        a0[1] = fmaf(v.x, q0.y, a0[1]); a1[1] = fmaf(v.y, q0.y, a1[1]);
        a0[2] = fmaf(v.x, q0.z, a0[2]); a1[2] = fmaf(v.y, q0.z, a1[2]);
        a0[3] = fmaf(v.x, q0.w, a0[3]); a1[3] = fmaf(v.y, q0.w, a1[3]);
        a0[4] = fmaf(v.x, q1.x, a0[4]); a1[4] = fmaf(v.y, q1.x, a1[4]);
        a0[5] = fmaf(v.x, q1.y, a0[5]); a1[5] = fmaf(v.y, q1.y, a1[5]);
        a0[6] = fmaf(v.x, q1.z, a0[6]); a1[6] = fmaf(v.y, q1.z, a1[6]);
        a0[7] = fmaf(v.x, q1.w, a0[7]); a1[7] = fmaf(v.y, q1.w, a1[7]);
    }

#pragma unroll
    for (int h = 0; h < NH; ++h) {
        float2 o;
        o.x = rintf(fminf(fmaxf(a0[h], 0.f), 4.f)) * 0.25f;
        o.y = rintf(fminf(fmaxf(a1[h], 0.f), 4.f)) * 0.25f;
        *(float2*)(a + ((size_t)b * NH + h) * NPIX + n0) = o;
    }
}

// ---------------------------------------------------------------------------
// K2: s partials, L1-resident a-windows.
// grid = 2048 (XCD-swizzled) = 16 b x 4 cblk(64 c) x 32 nblk(512 n);
// 8 blocks/CU = 32 waves/CU. Thread = (c_l = t>>2, nq = t&3): owns one c,
// n-quad strided by 16. Per-block a-window = 8h x 512n x 4B = 16 KB -> L1.
// fm: 16 c-rows x 64 B = dense lines. 4-lane shfl_xor reduce, no LDS.
// ---------------------------------------------------------------------------
__global__ __launch_bounds__(256) void k_s(const float* __restrict__ fm,
                                           const float* __restrict__ a,
                                           float* __restrict__ s_part) {
    const int d    = blockIdx.x;
    const int blk  = (d & 7) * 256 + (d >> 3);   // bijective: 2048 = 8 x 256
    const int b    = blk >> 7;                   // 128 blocks per b
    const int cblk = (blk >> 5) & 3;
    const int nblk = blk & 31;
    const int t    = threadIdx.x;
    const int c_l  = t >> 2;                     // 0..63
    const int nq   = t & 3;
    const int c    = cblk * 64 + c_l;
    const int n0   = nblk * 512;

    const float* fr = fm + ((size_t)b * DIMC + c) * NPIX + n0 + nq * 4;
    const float* ab = a + (size_t)b * NH * NPIX + n0 + nq * 4;

    float acc[NH];
#pragma unroll
    for (int h = 0; h < NH; ++h) acc[h] = 0.f;

#pragma unroll 2
    for (int j = 0; j < 32; ++j) {
        float4 v = *(const float4*)(fr + j * 16);
#pragma unroll
        for (int h = 0; h < NH; ++h) {
            float4 av = *(const float4*)(ab + (size_t)h * NPIX + j * 16);
            acc[h] += fmaf(v.x, av.x, fmaf(v.y, av.y, fmaf(v.z, av.z, v.w * av.w)));
        }
    }

    // 4-lane (nq) reduce
#pragma unroll
    for (int h = 0; h < NH; ++h) {
        acc[h] += __shfl_xor(acc[h], 1);
        acc[h] += __shfl_xor(acc[h], 2);
    }
    if (nq == 0) {
#pragma unroll
        for (int h = 0; h < NH; ++h)
            s_part[(((size_t)b * NSLAB + nblk) * NH + h) * DIMC + c] = acc[h];
    }
}

// ---------------------------------------------------------------------------
// K3: s = sum_slab s_part ; x = Wv*s ; p = Wp*x + bp ; LN ; spike -> scale
// ---------------------------------------------------------------------------
__global__ __launch_bounds__(256) void k_scale(const float* __restrict__ s_part,
                                               const float* __restrict__ Wkv,
                                               const float* __restrict__ Wp,
                                               const float* __restrict__ bp,
                                               const float* __restrict__ g,
                                               const float* __restrict__ beta,
                                               float* __restrict__ scale) {
    int b = blockIdx.x;
    int t = threadIdx.x;
    __shared__ float sL[NH][DIMC];
    __shared__ float xL[DIMC];
    __shared__ float red[8];
    __shared__ float mu_s, var_s;

    for (int h = 0; h < NH; ++h) {
        float acc = 0.f;
        for (int sl = 0; sl < NSLAB; ++sl)
            acc += s_part[(((size_t)b * NSLAB + sl) * NH + h) * DIMC + t];
        sL[h][t] = acc;
    }
    __syncthreads();

    {
        const float* wr = Wkv + (size_t)(DIMC + t) * DIMC;
        const float* sr = sL[t >> 5];
        float acc = 0.f;
        for (int cc = 0; cc < DIMC; cc += 4) {
            float4 w = *(const float4*)(wr + cc);
            acc = fmaf(w.x, sr[cc],     acc);
            acc = fmaf(w.y, sr[cc + 1], acc);
            acc = fmaf(w.z, sr[cc + 2], acc);
            acc = fmaf(w.w, sr[cc + 3], acc);
        }
        xL[t] = acc;
    }
    __syncthreads();

    float p;
    {
        const float* wr = Wp + (size_t)t * DIMC;
        float acc = 0.f;
        for (int i = 0; i < DIMC; i += 4) {
            float4 w = *(const float4*)(wr + i);
            acc = fmaf(w.x, xL[i],     acc);
            acc = fmaf(w.y, xL[i + 1], acc);
            acc = fmaf(w.z, xL[i + 2], acc);
            acc = fmaf(w.w, xL[i + 3], acc);
        }
        p = acc + bp[t];
    }

    int lane = t & 63, wid = t >> 6;
    float r = p;
#pragma unroll
    for (int off = 32; off > 0; off >>= 1) r += __shfl_down(r, off);
    if (lane == 0) red[wid] = r;
    __syncthreads();
    if (t == 0) mu_s = (red[0] + red[1] + red[2] + red[3]) * (1.f / 256.f);
    __syncthreads();
    float mu = mu_s;
    float dd = p - mu;
    float r2 = dd * dd;
#pragma unroll
    for (int off = 32; off > 0; off >>= 1) r2 += __shfl_down(r2, off);
    if (lane == 0) red[4 + wid] = r2;
    __syncthreads();
    if (t == 0) var_s = (red[4] + red[5] + red[6] + red[7]) * (1.f / 256.f);
    __syncthreads();

    float ln = dd * (1.0f / sqrtf(var_s + LN_EPS)) * g[t] + beta[t];
    scale[b * DIMC + t] = rintf(fminf(fmaxf(ln, 0.f), 4.f)) * 0.25f;
}

// ---------------------------------------------------------------------------
// K4: out = fm * scale[b][c]
// ---------------------------------------------------------------------------
__global__ __launch_bounds__(256) void k_out(const float* __restrict__ fm,
                                             const float* __restrict__ scale,
                                             float* __restrict__ out) {
    const size_t total4 = (size_t)BATCH * DIMC * NPIX / 4;
    size_t stride = (size_t)gridDim.x * blockDim.x;
    size_t gid = (size_t)blockIdx.x * blockDim.x + threadIdx.x;
    for (size_t i = gid; i < total4; i += stride) {
        float4 v = *(const float4*)(fm + i * 4);
        float sval = scale[i >> 12];
        float4 o;
        o.x = v.x * sval; o.y = v.y * sval; o.z = v.z * sval; o.w = v.w * sval;
        *(float4*)(out + i * 4) = o;
    }
}

// ---------------------------------------------------------------------------
extern "C" void kernel_launch(void* const* d_in, const int* in_sizes, int n_in,
                              void* d_out, int out_size, void* d_ws, size_t ws_size,
                              hipStream_t stream) {
    (void)in_sizes; (void)n_in; (void)out_size; (void)ws_size;
    const float* fm    = (const float*)d_in[0];
    const float* audio = (const float*)d_in[1];
    const float* Wq    = (const float*)d_in[2];
    const float* Wkv   = (const float*)d_in[3];
    const float* Wp    = (const float*)d_in[4];
    const float* bp    = (const float*)d_in[5];
    const float* g     = (const float*)d_in[6];
    const float* beta  = (const float*)d_in[7];
    float* out = (float*)d_out;

    char* ws = (char*)d_ws;
    float* qkT    = (float*)(ws);                                   // 128 KB
    float* a      = (float*)(ws + (size_t)131072);                  // 8 MB
    float* s_part = (float*)(ws + (size_t)131072 + 8388608);        // 4 MB
    float* scale  = (float*)(ws + (size_t)131072 + 8388608 + 4194304); // 16 KB

    hipLaunchKernelGGL(k_qk,    dim3(512),        dim3(256), 0, stream, audio, Wq, Wkv, qkT);
    hipLaunchKernelGGL(k_attn,  dim3(512),        dim3(256), 0, stream, fm, qkT, a);
    hipLaunchKernelGGL(k_s,     dim3(2048),       dim3(256), 0, stream, fm, a, s_part);
    hipLaunchKernelGGL(k_scale, dim3(BATCH),      dim3(256), 0, stream, s_part, Wkv, Wp, bp, g, beta, scale);
    hipLaunchKernelGGL(k_out,   dim3(2048),       dim3(256), 0, stream, fm, scale, out);
}

// Round 12
// 330.389 us; speedup vs baseline: 1.7714x; 1.0114x over previous
//
#include <hip/hip_runtime.h>
#include <math.h>

#define DIMC 256
#define NH 8
#define NPIX 16384          // 128*128
#define BATCH 16
#define ATT_SCALE 0.17677669529663687f   // 1/sqrt(32)
#define LN_EPS 1e-5f
#define NBLK_S 4            // n-splits in k_s

// ---------------------------------------------------------------------------
// K0: qkT[b][c][h], 512 blocks = 16 b x 32 c-slabs (R11-verified).
// ---------------------------------------------------------------------------
__global__ __launch_bounds__(256) void k_qk(const float* __restrict__ audio,
                                            const float* __restrict__ Wq,
                                            const float* __restrict__ Wkv,
                                            float* __restrict__ qkT) {
    const int blk = blockIdx.x;
    const int b   = blk >> 5;
    const int c0  = (blk & 31) * 8;
    const int t   = threadIdx.x;
    __shared__ float aud[DIMC];
    __shared__ float qL[DIMC];
    aud[t] = audio[b * DIMC + t];
    __syncthreads();
    {
        const float* wr = Wq + (size_t)t * DIMC;
        float acc = 0.f;
        for (int c = 0; c < DIMC; c += 4) {
            float4 w = *(const float4*)(wr + c);
            acc = fmaf(w.x, aud[c],     acc);
            acc = fmaf(w.y, aud[c + 1], acc);
            acc = fmaf(w.z, aud[c + 2], acc);
            acc = fmaf(w.w, aud[c + 3], acc);
        }
        qL[t] = acc;
    }
    __syncthreads();
    if (t < 64) {
        const int c = c0 + (t & 7);
        const int h = t >> 3;
        float acc = 0.f;
#pragma unroll
        for (int d = 0; d < 32; ++d)
            acc = fmaf(qL[h * 32 + d], Wkv[(size_t)(h * 32 + d) * DIMC + c], acc);
        qkT[((size_t)b * DIMC + c) * NH + h] = ATT_SCALE * acc;
    }
}

// ---------------------------------------------------------------------------
// K1: attn pass (R9 verbatim). 512 blocks x 256 thr, float2, unroll 8.
// Launched TWICE this round as a timing probe (writes identical values).
// ---------------------------------------------------------------------------
__global__ __launch_bounds__(256) void k_attn(const float* __restrict__ fm,
                                              const float* __restrict__ qkT,
                                              float* __restrict__ a) {
    int blk  = blockIdx.x;          // 512 = b*32 + nblk
    int b    = blk >> 5;
    int nblk = blk & 31;
    int t    = threadIdx.x;

    const int n0 = nblk * 512 + t * 2;
    const float* fmb = fm + (size_t)b * DIMC * NPIX + n0;
    const float* qb  = qkT + (size_t)b * DIMC * NH;

    float a0[NH], a1[NH];
#pragma unroll
    for (int h = 0; h < NH; ++h) { a0[h] = 0.f; a1[h] = 0.f; }

#pragma unroll 8
    for (int c = 0; c < DIMC; ++c) {
        float2 v  = *(const float2*)(fmb + (size_t)c * NPIX);
        float4 q0 = *(const float4*)(qb + c * NH);       // uniform -> s_load
        float4 q1 = *(const float4*)(qb + c * NH + 4);
        a0[0] = fmaf(v.x, q0.x, a0[0]); a1[0] = fmaf(v.y, q0.x, a1[0]);
        a0[1] = fmaf(v.x, q0.y, a0[1]); a1[1] = fmaf(v.y, q0.y, a1[1]);
        a0[2] = fmaf(v.x, q0.z, a0[2]); a1[2] = fmaf(v.y, q0.z, a1[2]);
        a0[3] = fmaf(v.x, q0.w, a0[3]); a1[3] = fmaf(v.y, q0.w, a1[3]);
        a0[4] = fmaf(v.x, q1.x, a0[4]); a1[4] = fmaf(v.y, q1.x, a1[4]);
        a0[5] = fmaf(v.x, q1.y, a0[5]); a1[5] = fmaf(v.y, q1.y, a1[5]);
        a0[6] = fmaf(v.x, q1.z, a0[6]); a1[6] = fmaf(v.y, q1.z, a1[6]);
        a0[7] = fmaf(v.x, q1.w, a0[7]); a1[7] = fmaf(v.y, q1.w, a1[7]);
    }

#pragma unroll
    for (int h = 0; h < NH; ++h) {
        float2 o;
        o.x = rintf(fminf(fmaxf(a0[h], 0.f), 4.f)) * 0.25f;
        o.y = rintf(fminf(fmaxf(a1[h], 0.f), 4.f)) * 0.25f;
        *(float2*)(a + ((size_t)b * NH + h) * NPIX + n0) = o;
    }
}

// ---------------------------------------------------------------------------
// K2: s partials (R9 verbatim). 1024 blocks XCD-swizzled, thread=(c16,nq16).
// ---------------------------------------------------------------------------
__global__ __launch_bounds__(256) void k_s(const float* __restrict__ fm,
                                           const float* __restrict__ a,
                                           float* __restrict__ s_part) {
    int d    = blockIdx.x;
    int blk  = (d & 7) * 128 + (d >> 3);   // bijective: 1024 = 8 x 128
    int b    = blk >> 6;
    int nblk = (blk >> 4) & 3;
    int cblk = blk & 15;
    int t    = threadIdx.x;
    int c_l  = t >> 4;
    int nq   = t & 15;
    int c    = cblk * 16 + c_l;

    const float* fr = fm + ((size_t)b * DIMC + c) * NPIX + nblk * 4096 + nq * 4;
    const float* ab = a + (size_t)b * NH * NPIX + nblk * 4096 + nq * 4;

    float acc[NH];
#pragma unroll
    for (int h = 0; h < NH; ++h) acc[h] = 0.f;

#pragma unroll 2
    for (int j = 0; j < 64; ++j) {
        float4 v = *(const float4*)(fr + j * 64);
#pragma unroll
        for (int h = 0; h < NH; ++h) {
            float4 av = *(const float4*)(ab + (size_t)h * NPIX + j * 64);
            acc[h] += fmaf(v.x, av.x, fmaf(v.y, av.y, fmaf(v.z, av.z, v.w * av.w)));
        }
    }

    __shared__ float red[256 * NH];    // 8 KB
#pragma unroll
    for (int h = 0; h < NH; ++h) red[t * NH + h] = acc[h];
    __syncthreads();

    if (t < 128) {
        int cl = t >> 3, h = t & 7;
        float sum = 0.f;
#pragma unroll
        for (int q = 0; q < 16; ++q)
            sum += red[(cl * 16 + q) * NH + h];
        s_part[(((size_t)b * NBLK_S + nblk) * NH + h) * DIMC + cblk * 16 + cl] = sum;
    }
}

// ---------------------------------------------------------------------------
// K3: s = sum_slab s_part ; x = Wv*s ; p = Wp*x + bp ; LN ; spike -> scale
// ---------------------------------------------------------------------------
__global__ __launch_bounds__(256) void k_scale(const float* __restrict__ s_part,
                                               const float* __restrict__ Wkv,
                                               const float* __restrict__ Wp,
                                               const float* __restrict__ bp,
                                               const float* __restrict__ g,
                                               const float* __restrict__ beta,
                                               float* __restrict__ scale) {
    int b = blockIdx.x;
    int t = threadIdx.x;
    __shared__ float sL[NH][DIMC];
    __shared__ float xL[DIMC];
    __shared__ float red[8];
    __shared__ float mu_s, var_s;

    for (int h = 0; h < NH; ++h) {
        float acc = 0.f;
        for (int sl = 0; sl < NBLK_S; ++sl)
            acc += s_part[(((size_t)b * NBLK_S + sl) * NH + h) * DIMC + t];
        sL[h][t] = acc;
    }
    __syncthreads();

    {
        const float* wr = Wkv + (size_t)(DIMC + t) * DIMC;
        const float* sr = sL[t >> 5];
        float acc = 0.f;
        for (int cc = 0; cc < DIMC; cc += 4) {
            float4 w = *(const float4*)(wr + cc);
            acc = fmaf(w.x, sr[cc],     acc);
            acc = fmaf(w.y, sr[cc + 1], acc);
            acc = fmaf(w.z, sr[cc + 2], acc);
            acc = fmaf(w.w, sr[cc + 3], acc);
        }
        xL[t] = acc;
    }
    __syncthreads();

    float p;
    {
        const float* wr = Wp + (size_t)t * DIMC;
        float acc = 0.f;
        for (int i = 0; i < DIMC; i += 4) {
            float4 w = *(const float4*)(wr + i);
            acc = fmaf(w.x, xL[i],     acc);
            acc = fmaf(w.y, xL[i + 1], acc);
            acc = fmaf(w.z, xL[i + 2], acc);
            acc = fmaf(w.w, xL[i + 3], acc);
        }
        p = acc + bp[t];
    }

    int lane = t & 63, wid = t >> 6;
    float r = p;
#pragma unroll
    for (int off = 32; off > 0; off >>= 1) r += __shfl_down(r, off);
    if (lane == 0) red[wid] = r;
    __syncthreads();
    if (t == 0) mu_s = (red[0] + red[1] + red[2] + red[3]) * (1.f / 256.f);
    __syncthreads();
    float mu = mu_s;
    float dd = p - mu;
    float r2 = dd * dd;
#pragma unroll
    for (int off = 32; off > 0; off >>= 1) r2 += __shfl_down(r2, off);
    if (lane == 0) red[4 + wid] = r2;
    __syncthreads();
    if (t == 0) var_s = (red[4] + red[5] + red[6] + red[7]) * (1.f / 256.f);
    __syncthreads();

    float ln = dd * (1.0f / sqrtf(var_s + LN_EPS)) * g[t] + beta[t];
    scale[b * DIMC + t] = rintf(fminf(fmaxf(ln, 0.f), 4.f)) * 0.25f;
}

// ---------------------------------------------------------------------------
// K4: out = fm * scale[b][c]
// ---------------------------------------------------------------------------
__global__ __launch_bounds__(256) void k_out(const float* __restrict__ fm,
                                             const float* __restrict__ scale,
                                             float* __restrict__ out) {
    const size_t total4 = (size_t)BATCH * DIMC * NPIX / 4;
    size_t stride = (size_t)gridDim.x * blockDim.x;
    size_t gid = (size_t)blockIdx.x * blockDim.x + threadIdx.x;
    for (size_t i = gid; i < total4; i += stride) {
        float4 v = *(const float4*)(fm + i * 4);
        float sval = scale[i >> 12];
        float4 o;
        o.x = v.x * sval; o.y = v.y * sval; o.z = v.z * sval; o.w = v.w * sval;
        *(float4*)(out + i * 4) = o;
    }
}

// ---------------------------------------------------------------------------
extern "C" void kernel_launch(void* const* d_in, const int* in_sizes, int n_in,
                              void* d_out, int out_size, void* d_ws, size_t ws_size,
                              hipStream_t stream) {
    (void)in_sizes; (void)n_in; (void)out_size; (void)ws_size;
    const float* fm    = (const float*)d_in[0];
    const float* audio = (const float*)d_in[1];
    const float* Wq    = (const float*)d_in[2];
    const float* Wkv   = (const float*)d_in[3];
    const float* Wp    = (const float*)d_in[4];
    const float* bp    = (const float*)d_in[5];
    const float* g     = (const float*)d_in[6];
    const float* beta  = (const float*)d_in[7];
    float* out = (float*)d_out;

    char* ws = (char*)d_ws;
    float* qkT    = (float*)(ws);                                   // 128 KB
    float* a      = (float*)(ws + (size_t)131072);                  // 8 MB
    float* s_part = (float*)(ws + (size_t)131072 + 8388608);        // 512 KB
    float* scale  = (float*)(ws + (size_t)131072 + 8388608 + 524288); // 16 KB

    hipLaunchKernelGGL(k_qk,    dim3(512),        dim3(256), 0, stream, audio, Wq, Wkv, qkT);
    // PROBE: k_attn dispatched twice (identical output); delta vs R9 = t_attn
    hipLaunchKernelGGL(k_attn,  dim3(512),        dim3(256), 0, stream, fm, qkT, a);
    hipLaunchKernelGGL(k_attn,  dim3(512),        dim3(256), 0, stream, fm, qkT, a);
    hipLaunchKernelGGL(k_s,     dim3(1024),       dim3(256), 0, stream, fm, a, s_part);
    hipLaunchKernelGGL(k_scale, dim3(BATCH),      dim3(256), 0, stream, s_part, Wkv, Wp, bp, g, beta, scale);
    hipLaunchKernelGGL(k_out,   dim3(2048),       dim3(256), 0, stream, fm, scale, out);
}